// Round 1
// baseline (267.600 us; speedup 1.0000x reference)
//
#include <hip/hip_runtime.h>
#include <math.h>

// Problem constants
#define BB    64
#define TT    512
#define TWOH  1024
#define RPW   8                  // t-rows per WAVE (online-softmax serial depth)
#define WPB   4                  // waves per block (256 threads)
#define NG    (TT / RPW)         // 64 score-chunks per b (one per wave)
#define KSPLIT 4                 // d-dim split for k_qgemm
#define NP_STRIDE ((TT + 1) * TWOH)  // 513*1024

// native clang vector type (vectorized loads/stores)
typedef float vfloat4 __attribute__((ext_vector_type(4)));

// NOTE (R3 post-mortem): __builtin_nontemporal_store on out_np caused
// post-timing divergence under the harness's re-poison path — no nt stores.
// NOTE (this round): k_scores_ct rebuilt barrier-free. Old 4-phase version
// stalled at VGPR=56 (compiler refused to keep pv[16] resident; 26 µs
// residency per wave for 33 KB moved). New structure: each wave owns 8 rows,
// flash-style online softmax per row, loaded registers die immediately
// (copy-store + dot + ct-FMA), one-row register double-buffer, zero LDS.

// -------------------------------------------------------------------------
// K1: partial GEMM  qpart[k][b][e] = sum_{d in k-slice} h[b,d] * W[d,e]
// grid = (4 e-chunks, 64 b, 4 k-slices) = 1024 blocks -> 4 blocks/CU.
// -------------------------------------------------------------------------
__global__ __launch_bounds__(256) void k_qgemm(const float* __restrict__ h,
                                               const float* __restrict__ W,
                                               float* __restrict__ qpart) {
    const int tid = threadIdx.x;
    const int e   = blockIdx.x * 256 + tid;      // 0..1023
    const int b   = blockIdx.y;                  // 0..63
    const int k   = blockIdx.z;                  // 0..3
    const int d0  = k * (TWOH / KSPLIT);         // 256-wide d slice

    __shared__ float sh[TWOH / KSPLIT];
    sh[tid] = h[b * TWOH + d0 + tid];
    __syncthreads();

    const float* __restrict__ Wp = W + (size_t)d0 * TWOH + e;
    float acc = 0.f;
    #pragma unroll 16
    for (int d = 0; d < TWOH / KSPLIT; ++d)
        acc = fmaf(sh[d], Wp[(size_t)d * TWOH], acc);

    qpart[((size_t)k * BB + b) * TWOH + e] = acc;
}

// -------------------------------------------------------------------------
// K2: barrier-free. Each wave owns RPW=8 consecutive t-rows of one b.
// Lane l covers e = 4l + 256j (j=0..3): 4 coalesced float4 loads per row.
// Per row: prefetch next row -> copy-store -> wave-local dot (16 FMA +
// 6-step butterfly) -> wave-uniform online-softmax update of (m,l,ct).
// No LDS, no __syncthreads, nothing lives past its row.
// grid = (NG/WPB=16, 64 b) = 1024 blocks = 4/CU, 16 waves/CU resident.
// -------------------------------------------------------------------------
__global__ __launch_bounds__(256, 4) void k_scores_ct(const float* __restrict__ prev,
                                                      const float* __restrict__ qpart,
                                                      float* __restrict__ out_np,
                                                      float* __restrict__ ws_m,
                                                      float* __restrict__ ws_l,
                                                      float* __restrict__ ws_ct) {
    const int tid  = threadIdx.x;
    const int lane = tid & 63;
    const int wid  = tid >> 6;
    const int b    = blockIdx.y;                 // 0..63
    const int g    = blockIdx.x * WPB + wid;     // chunk 0..NG-1
    const int t0   = g * RPW;

    // q[b] at this lane's 16 e-positions = sum of 4 k-partials (L2-hot).
    const vfloat4* __restrict__ qp = (const vfloat4*)qpart;
    const int qb0 = ((0 * BB + b) * 256) + lane;
    const int qb1 = ((1 * BB + b) * 256) + lane;
    const int qb2 = ((2 * BB + b) * 256) + lane;
    const int qb3 = ((3 * BB + b) * 256) + lane;
    vfloat4 q0 = qp[qb0      ] + qp[qb1      ] + qp[qb2      ] + qp[qb3      ];
    vfloat4 q1 = qp[qb0 +  64] + qp[qb1 +  64] + qp[qb2 +  64] + qp[qb3 +  64];
    vfloat4 q2 = qp[qb0 + 128] + qp[qb1 + 128] + qp[qb2 + 128] + qp[qb3 + 128];
    vfloat4 q3 = qp[qb0 + 192] + qp[qb1 + 192] + qp[qb2 + 192] + qp[qb3 + 192];

    const vfloat4* __restrict__ prow =
        (const vfloat4*)(prev + ((size_t)b * TT + (size_t)t0) * TWOH) + lane;
    vfloat4* __restrict__ nprow =
        (vfloat4*)(out_np + (size_t)b * NP_STRIDE + (size_t)t0 * TWOH) + lane;

    // prime the one-row register double-buffer
    vfloat4 c0 = prow[0], c1 = prow[64], c2 = prow[128], c3 = prow[192];

    float m = -INFINITY;
    float l = 0.f;
    vfloat4 ct0 = (vfloat4)(0.f), ct1 = (vfloat4)(0.f),
            ct2 = (vfloat4)(0.f), ct3 = (vfloat4)(0.f);

    #pragma unroll
    for (int r = 0; r < RPW; ++r) {
        vfloat4 n0, n1, n2, n3;
        if (r + 1 < RPW) {
            const int o = (r + 1) * 256;
            n0 = prow[o]; n1 = prow[o + 64]; n2 = prow[o + 128]; n3 = prow[o + 192];
        }

        // fused concat-copy of the current row (registers already here)
        const int so = r * 256;
        nprow[so] = c0; nprow[so + 64] = c1; nprow[so + 128] = c2; nprow[so + 192] = c3;

        // wave-local dot: 4 short FMA chains, then combine
        float d0 = c0.x * q0.x; d0 = fmaf(c0.y, q0.y, d0);
        d0 = fmaf(c0.z, q0.z, d0); d0 = fmaf(c0.w, q0.w, d0);
        float d1 = c1.x * q1.x; d1 = fmaf(c1.y, q1.y, d1);
        d1 = fmaf(c1.z, q1.z, d1); d1 = fmaf(c1.w, q1.w, d1);
        float d2 = c2.x * q2.x; d2 = fmaf(c2.y, q2.y, d2);
        d2 = fmaf(c2.z, q2.z, d2); d2 = fmaf(c2.w, q2.w, d2);
        float d3 = c3.x * q3.x; d3 = fmaf(c3.y, q3.y, d3);
        d3 = fmaf(c3.z, q3.z, d3); d3 = fmaf(c3.w, q3.w, d3);
        float pd = (d0 + d1) + (d2 + d3);

        // 64-lane butterfly: every lane ends with the full row score
        #pragma unroll
        for (int off = 32; off > 0; off >>= 1)
            pd += __shfl_xor(pd, off, 64);

        // online softmax update — pd is wave-uniform, branch is uniform.
        if (pd > m) {                       // first row: m=-inf -> s=exp(-inf)=0
            const float s = __expf(m - pd);
            l *= s;
            ct0 = ct0 * s; ct1 = ct1 * s; ct2 = ct2 * s; ct3 = ct3 * s;
            m = pd;
        }
        const float a = __expf(pd - m);
        l += a;
        ct0.x = fmaf(a, c0.x, ct0.x); ct0.y = fmaf(a, c0.y, ct0.y);
        ct0.z = fmaf(a, c0.z, ct0.z); ct0.w = fmaf(a, c0.w, ct0.w);
        ct1.x = fmaf(a, c1.x, ct1.x); ct1.y = fmaf(a, c1.y, ct1.y);
        ct1.z = fmaf(a, c1.z, ct1.z); ct1.w = fmaf(a, c1.w, ct1.w);
        ct2.x = fmaf(a, c2.x, ct2.x); ct2.y = fmaf(a, c2.y, ct2.y);
        ct2.z = fmaf(a, c2.z, ct2.z); ct2.w = fmaf(a, c2.w, ct2.w);
        ct3.x = fmaf(a, c3.x, ct3.x); ct3.y = fmaf(a, c3.y, ct3.y);
        ct3.z = fmaf(a, c3.z, ct3.z); ct3.w = fmaf(a, c3.w, ct3.w);

        if (r + 1 < RPW) { c0 = n0; c1 = n1; c2 = n2; c3 = n3; }
    }

    // per-wave partials
    const size_t wsb = (size_t)b * NG + g;
    vfloat4* __restrict__ wc = (vfloat4*)ws_ct + wsb * 256 + lane;
    wc[0] = ct0; wc[64] = ct1; wc[128] = ct2; wc[192] = ct3;
    if (lane == 0) {
        ws_m[wsb] = m;
        ws_l[wsb] = l;
    }
}

// -------------------------------------------------------------------------
// K3: combine NG=64 chunk partials per b; also new_prev[b,512,:] = h[b,:].
// coef recomputed on the fly (uniform scalar loads) -> no coef[64] spill.
// grid = (4 e-chunks, 64 b) = 256 blocks; thread owns one e.
// -------------------------------------------------------------------------
__global__ __launch_bounds__(256) void k_finalize(const float* __restrict__ h,
                                                  const float* __restrict__ ws_m,
                                                  const float* __restrict__ ws_l,
                                                  const float* __restrict__ ws_ct,
                                                  float* __restrict__ out_ct,
                                                  float* __restrict__ out_np) {
    const int tid = threadIdx.x;
    const int e   = blockIdx.x * 256 + tid;
    const int b   = blockIdx.y;

    const float* __restrict__ wm = ws_m + b * NG;
    const float* __restrict__ wl = ws_l + b * NG;

    float M = -INFINITY;
    #pragma unroll
    for (int i = 0; i < NG; ++i) M = fmaxf(M, wm[i]);

    float L = 0.f;
    #pragma unroll
    for (int i = 0; i < NG; ++i) L = fmaf(__expf(wm[i] - M), wl[i], L);
    const float inv = 1.0f / L;

    const float* __restrict__ cp = ws_ct + (size_t)b * NG * TWOH + e;
    float acc = 0.f;
    #pragma unroll
    for (int i = 0; i < NG; ++i)
        acc = fmaf(__expf(wm[i] - M), cp[(size_t)i * TWOH], acc);
    out_ct[b * TWOH + e] = acc * inv;

    // concat row: new_prev[b, T, :] = h[b, :]
    out_np[(size_t)b * NP_STRIDE + (size_t)TT * TWOH + e] = h[b * TWOH + e];
}

extern "C" void kernel_launch(void* const* d_in, const int* in_sizes, int n_in,
                              void* d_out, int out_size, void* d_ws, size_t ws_size,
                              hipStream_t stream) {
    const float* h    = (const float*)d_in[0];   // (64, 1024)
    const float* prev = (const float*)d_in[1];   // (64, 512, 1024)
    const float* W    = (const float*)d_in[2];   // (1, 1024, 1024)
    float* out    = (float*)d_out;
    float* out_ct = out;                         // (64, 1024)
    float* out_np = out + BB * TWOH;             // (64, 513, 1024)

    // ws layout (floats): qpart[4*64*1024] | m[64*64] | l[64*64] | ct[64*64*1024]
    // total ~= 17.9 MB. Fallback if ws is ever tight: RPW=16 halves ct.
    float* qpart = (float*)d_ws;
    float* wsm   = qpart + KSPLIT * BB * TWOH;
    float* wsl   = wsm + BB * NG;
    float* wsc   = wsl + BB * NG;

    k_qgemm<<<dim3(4, BB, KSPLIT), 256, 0, stream>>>(h, W, qpart);
    k_scores_ct<<<dim3(NG / WPB, BB), 256, 0, stream>>>(prev, qpart, out_np, wsm, wsl, wsc);
    k_finalize<<<dim3(4, BB), 256, 0, stream>>>(h, wsm, wsl, wsc, out_ct, out_np);
}

// Round 2
// 262.082 us; speedup vs baseline: 1.0211x; 1.0211x over previous
//
#include <hip/hip_runtime.h>
#include <math.h>

// Problem constants
#define BB    64
#define TT    512
#define TWOH  1024
#define RPW   4                  // t-rows per WAVE (straight-line, no loop-carry)
#define WPB   4                  // waves per block (256 threads)
#define TC    (RPW * WPB)        // 16 rows per block-chunk
#define NCHUNK (TT / TC)         // 32 chunk-partials per b
#define KSPLIT 4                 // d-dim split for k_qgemm
#define NP_STRIDE ((TT + 1) * TWOH)  // 513*1024

// native clang vector type (vectorized loads/stores)
typedef float vfloat4 __attribute__((ext_vector_type(4)));

// NOTE (R3 post-mortem): __builtin_nontemporal_store on out_np caused
// post-timing divergence under the harness's re-poison path — no nt stores.
// NOTE (R1 post-mortem): ANY loop-carried register structure in k_scores_ct
// (pv[16] phase version, or rotating one-row prefetch) gets de-prefetched by
// the register-pressure heuristic: VGPR_Count came back 56/52 both times and
// loads serialized at ~2.5 TB/s. This version is fully straight-lined per
// wave (RPW=4): 16 loads issued back-to-back, acyclic dataflow, nothing for
// the scheduler to sink. Diagnostic: if VGPR_Count < 64, it happened again.

// -------------------------------------------------------------------------
// K1: partial GEMM  qpart[k][b][e] = sum_{d in k-slice} h[b,d] * W[d,e]
// grid = (4 e-chunks, 64 b, 4 k-slices) = 1024 blocks -> 4 blocks/CU.
// -------------------------------------------------------------------------
__global__ __launch_bounds__(256) void k_qgemm(const float* __restrict__ h,
                                               const float* __restrict__ W,
                                               float* __restrict__ qpart) {
    const int tid = threadIdx.x;
    const int e   = blockIdx.x * 256 + tid;      // 0..1023
    const int b   = blockIdx.y;                  // 0..63
    const int k   = blockIdx.z;                  // 0..3
    const int d0  = k * (TWOH / KSPLIT);         // 256-wide d slice

    __shared__ float sh[TWOH / KSPLIT];
    sh[tid] = h[b * TWOH + d0 + tid];
    __syncthreads();

    const float* __restrict__ Wp = W + (size_t)d0 * TWOH + e;
    float acc = 0.f;
    #pragma unroll 16
    for (int d = 0; d < TWOH / KSPLIT; ++d)
        acc = fmaf(sh[d], Wp[(size_t)d * TWOH], acc);

    qpart[((size_t)k * BB + b) * TWOH + e] = acc;
}

// -------------------------------------------------------------------------
// K2: each wave owns RPW=4 consecutive t-rows, fully straight-lined:
//   16 float4 loads (MLP=16) -> 16 copy-stores -> 4 wave dots (butterfly)
//   -> chunk-local softmax over the 4 wave-uniform scores (no branch)
//   -> ct accumulate in registers -> 4-wave LDS combine (one barrier)
//   -> one 16-row partial (m,l,ct) per block.
// grid = (NCHUNK=32, 64 b) = 2048 blocks = 8/CU target.
// -------------------------------------------------------------------------
__global__ __launch_bounds__(256, 4) void k_scores_ct(const float* __restrict__ prev,
                                                      const float* __restrict__ qpart,
                                                      float* __restrict__ out_np,
                                                      float* __restrict__ ws_m,
                                                      float* __restrict__ ws_l,
                                                      float* __restrict__ ws_ct) {
    const int tid  = threadIdx.x;
    const int lane = tid & 63;
    const int wid  = tid >> 6;
    const int c    = blockIdx.x;                 // chunk 0..31
    const int b    = blockIdx.y;                 // 0..63
    const int t0   = c * TC + wid * RPW;         // this wave's first row

    __shared__ float s_ct[WPB][TWOH];
    __shared__ float s_m[WPB];
    __shared__ float s_l[WPB];

    // q[b] at this lane's 16 e-positions = sum of 4 k-partials (L2-hot).
    const vfloat4* __restrict__ qp = (const vfloat4*)qpart;
    vfloat4 q[4];
    #pragma unroll
    for (int j = 0; j < 4; ++j)
        q[j] = qp[(0 * BB + b) * 256 + j * 64 + lane]
             + qp[(1 * BB + b) * 256 + j * 64 + lane]
             + qp[(2 * BB + b) * 256 + j * 64 + lane]
             + qp[(3 * BB + b) * 256 + j * 64 + lane];

    const vfloat4* __restrict__ prow =
        (const vfloat4*)(prev + ((size_t)b * TT + (size_t)t0) * TWOH) + lane;
    vfloat4* __restrict__ nprow =
        (vfloat4*)(out_np + (size_t)b * NP_STRIDE + (size_t)t0 * TWOH) + lane;

    // all 16 row-loads issued back-to-back (acyclic, nothing to sink)
    vfloat4 cv[RPW][4];
    #pragma unroll
    for (int r = 0; r < RPW; ++r)
        #pragma unroll
        for (int j = 0; j < 4; ++j)
            cv[r][j] = prow[r * 256 + j * 64];

    // fused concat-copy (first consumer; compiler drains vmcnt progressively)
    #pragma unroll
    for (int r = 0; r < RPW; ++r)
        #pragma unroll
        for (int j = 0; j < 4; ++j)
            nprow[r * 256 + j * 64] = cv[r][j];

    // wave-local dots: 4 independent chains per row, then combine
    float pd[RPW];
    #pragma unroll
    for (int r = 0; r < RPW; ++r) {
        float d0 = cv[r][0].x * q[0].x;
        d0 = fmaf(cv[r][0].y, q[0].y, d0);
        d0 = fmaf(cv[r][0].z, q[0].z, d0);
        d0 = fmaf(cv[r][0].w, q[0].w, d0);
        float d1 = cv[r][1].x * q[1].x;
        d1 = fmaf(cv[r][1].y, q[1].y, d1);
        d1 = fmaf(cv[r][1].z, q[1].z, d1);
        d1 = fmaf(cv[r][1].w, q[1].w, d1);
        float d2 = cv[r][2].x * q[2].x;
        d2 = fmaf(cv[r][2].y, q[2].y, d2);
        d2 = fmaf(cv[r][2].z, q[2].z, d2);
        d2 = fmaf(cv[r][2].w, q[2].w, d2);
        float d3 = cv[r][3].x * q[3].x;
        d3 = fmaf(cv[r][3].y, q[3].y, d3);
        d3 = fmaf(cv[r][3].z, q[3].z, d3);
        d3 = fmaf(cv[r][3].w, q[3].w, d3);
        pd[r] = (d0 + d1) + (d2 + d3);
    }
    #pragma unroll
    for (int r = 0; r < RPW; ++r)
        #pragma unroll
        for (int off = 32; off > 0; off >>= 1)
            pd[r] += __shfl_xor(pd[r], off, 64);

    // chunk-local softmax over 4 wave-uniform scores: no branch, no rescale
    const float m = fmaxf(fmaxf(pd[0], pd[1]), fmaxf(pd[2], pd[3]));
    float a[RPW];
    float l = 0.f;
    #pragma unroll
    for (int r = 0; r < RPW; ++r) {
        a[r] = __expf(pd[r] - m);
        l += a[r];
    }
    vfloat4 ct[4];
    #pragma unroll
    for (int j = 0; j < 4; ++j) ct[j] = (vfloat4)(0.f);
    #pragma unroll
    for (int r = 0; r < RPW; ++r)
        #pragma unroll
        for (int j = 0; j < 4; ++j) {
            ct[j].x = fmaf(a[r], cv[r][j].x, ct[j].x);
            ct[j].y = fmaf(a[r], cv[r][j].y, ct[j].y);
            ct[j].z = fmaf(a[r], cv[r][j].z, ct[j].z);
            ct[j].w = fmaf(a[r], cv[r][j].w, ct[j].w);
        }

    // 4-wave combine via LDS (single barrier, at the very end)
    vfloat4* __restrict__ sct = (vfloat4*)&s_ct[wid][0];
    #pragma unroll
    for (int j = 0; j < 4; ++j) sct[j * 64 + lane] = ct[j];
    if (lane == 0) { s_m[wid] = m; s_l[wid] = l; }
    __syncthreads();

    const float M = fmaxf(fmaxf(s_m[0], s_m[1]), fmaxf(s_m[2], s_m[3]));
    float L = 0.f;
    float co[WPB];
    #pragma unroll
    for (int w = 0; w < WPB; ++w) {
        co[w] = __expf(s_m[w] - M);
        L = fmaf(co[w], s_l[w], L);
    }
    vfloat4 o = (vfloat4)(0.f);
    #pragma unroll
    for (int w = 0; w < WPB; ++w) {
        const vfloat4 v = ((const vfloat4*)&s_ct[w][0])[tid];
        o.x = fmaf(co[w], v.x, o.x);
        o.y = fmaf(co[w], v.y, o.y);
        o.z = fmaf(co[w], v.z, o.z);
        o.w = fmaf(co[w], v.w, o.w);
    }
    ((vfloat4*)(ws_ct + ((size_t)b * NCHUNK + c) * TWOH))[tid] = o;
    if (tid == 0) {
        ws_m[b * NCHUNK + c] = M;
        ws_l[b * NCHUNK + c] = L;
    }
}

// -------------------------------------------------------------------------
// K3: combine NCHUNK=32 chunk partials per b; also new_prev[b,512,:] = h[b,:].
// Single fused loop: coef computed once, feeds both L and the ct accumulate.
// grid = (4 e-chunks, 64 b) = 256 blocks; thread owns one e.
// -------------------------------------------------------------------------
__global__ __launch_bounds__(256) void k_finalize(const float* __restrict__ h,
                                                  const float* __restrict__ ws_m,
                                                  const float* __restrict__ ws_l,
                                                  const float* __restrict__ ws_ct,
                                                  float* __restrict__ out_ct,
                                                  float* __restrict__ out_np) {
    const int tid = threadIdx.x;
    const int e   = blockIdx.x * 256 + tid;
    const int b   = blockIdx.y;

    const float* __restrict__ wm = ws_m + b * NCHUNK;
    const float* __restrict__ wl = ws_l + b * NCHUNK;

    float M = -INFINITY;
    #pragma unroll
    for (int i = 0; i < NCHUNK; ++i) M = fmaxf(M, wm[i]);

    const float* __restrict__ cp = ws_ct + (size_t)b * NCHUNK * TWOH + e;
    float L = 0.f;
    float acc = 0.f;
    #pragma unroll
    for (int i = 0; i < NCHUNK; ++i) {
        const float ce = __expf(wm[i] - M);
        L   = fmaf(ce, wl[i], L);
        acc = fmaf(ce, cp[(size_t)i * TWOH], acc);
    }
    out_ct[b * TWOH + e] = acc * (1.0f / L);

    // concat row: new_prev[b, T, :] = h[b, :]
    out_np[(size_t)b * NP_STRIDE + (size_t)TT * TWOH + e] = h[b * TWOH + e];
}

extern "C" void kernel_launch(void* const* d_in, const int* in_sizes, int n_in,
                              void* d_out, int out_size, void* d_ws, size_t ws_size,
                              hipStream_t stream) {
    const float* h    = (const float*)d_in[0];   // (64, 1024)
    const float* prev = (const float*)d_in[1];   // (64, 512, 1024)
    const float* W    = (const float*)d_in[2];   // (1, 1024, 1024)
    float* out    = (float*)d_out;
    float* out_ct = out;                         // (64, 1024)
    float* out_np = out + BB * TWOH;             // (64, 513, 1024)

    // ws layout (floats): qpart[4*64*1024] | m[64*32] | l[64*32] | ct[64*32*1024]
    // total ~= 9.4 MB.
    float* qpart = (float*)d_ws;
    float* wsm   = qpart + KSPLIT * BB * TWOH;
    float* wsl   = wsm + BB * NCHUNK;
    float* wsc   = wsl + BB * NCHUNK;

    k_qgemm<<<dim3(4, BB, KSPLIT), 256, 0, stream>>>(h, W, qpart);
    k_scores_ct<<<dim3(NCHUNK, BB), 256, 0, stream>>>(prev, qpart, out_np, wsm, wsl, wsc);
    k_finalize<<<dim3(4, BB), 256, 0, stream>>>(h, wsm, wsl, wsc, out_ct, out_np);
}